// Round 2
// baseline (196.589 us; speedup 1.0000x reference)
//
#include <hip/hip_runtime.h>
#include <math.h>

// B=65536, F=512, K=1299.
// einsum+gather == one dot/row vs labeled center.
// R1: same-address atomics serialize @13.3ns each (217us). R2: ws partials.
// R3: batched rows/wave (~50us kernel). R4/R5: nt loads neutral. R6: occupancy
// 2x (ROWS 8->4) neutral -> NOT latency-bound.
// R7 theory: traffic arithmetic. input stream 134MB + center gathers 134MB
// (centers thrashed out of 4MB/XCD L2 by the 17MB/XCD input stream) = 268MB
// beyond-L2. 268MB/43us = 6.24 TB/s = the achievable ceiling. Kernel is at
// the roofline FOR 2x THE IDEAL BYTES. nt was neutral because nt still
// allocates in L2 (evict-first hint), so the thrash happens regardless.
// R7 fix: input loads via __hip_atomic_load(AGENT, relaxed) -> global_load
// with sc1 = true L2 bypass (agent scope cannot hit non-cross-coherent
// per-XCD L2). Centers stay L2-resident; center HBM traffic drops to ~21MB
// cold misses. Both input+centers use 4x8B contiguous-slot loads (k*64+lane)
// so each instruction covers a dense 512B segment (bypassed reads must be
// dense per-instruction). Predict main 43->~26us, total 192->~175us.

#define F_DIM 512
#define ROWS_PER_WAVE 4
#define WAVES_PER_BLOCK 4
#define NUM_BLOCKS 4096   // 4096 blk * 4 waves * 4 rows = 65536 rows exactly

typedef float fx2 __attribute__((ext_vector_type(2)));

union U64F2 { unsigned long long u; fx2 f; };

__global__ __launch_bounds__(256) void prediction_loss_kernel(
    const float* __restrict__ input,    // (B, F)  -- streamed, zero reuse
    const float* __restrict__ factor,   // (B,)
    const int*   __restrict__ label,    // (B,)
    const float* __restrict__ centers,  // (K, F)  -- 2.66 MB, heavy reuse
    float* __restrict__ out,            // [0]=loss, [1..B]=predict_a
    float* __restrict__ partials)       // (NUM_BLOCKS,)
{
    const int wave = threadIdx.x >> 6;
    const int lane = threadIdx.x & 63;
    const int b0 = (blockIdx.x * WAVES_PER_BLOCK + wave) * ROWS_PER_WAVE;

    // --- label indices (scalarized) ---
    int c[ROWS_PER_WAVE];
    #pragma unroll
    for (int r = 0; r < ROWS_PER_WAVE; ++r)
        c[r] = __builtin_amdgcn_readfirstlane(label[b0 + r]);

    // --- center loads: NORMAL caching (allocate in L2, heavy reuse) ---
    U64F2 w[ROWS_PER_WAVE][4];
    #pragma unroll
    for (int r = 0; r < ROWS_PER_WAVE; ++r) {
        const unsigned long long* __restrict__ cp =
            (const unsigned long long*)(centers + (size_t)c[r] * F_DIM);
        #pragma unroll
        for (int k = 0; k < 4; ++k)
            w[r][k].u = cp[k * 64 + lane];
    }

    // --- input loads: AGENT-scope relaxed -> sc1, bypasses per-XCD L2.
    //     Stream no longer evicts the centers. ---
    U64F2 a[ROWS_PER_WAVE][4];
    #pragma unroll
    for (int r = 0; r < ROWS_PER_WAVE; ++r) {
        const unsigned long long* __restrict__ ip =
            (const unsigned long long*)(input + (size_t)(b0 + r) * F_DIM);
        #pragma unroll
        for (int k = 0; k < 4; ++k)
            a[r][k].u = __hip_atomic_load(ip + k * 64 + lane,
                                          __ATOMIC_RELAXED,
                                          __HIP_MEMORY_SCOPE_AGENT);
    }

    // --- 4 independent partial dots (8 floats/lane/row) ---
    float dot[ROWS_PER_WAVE];
    #pragma unroll
    for (int r = 0; r < ROWS_PER_WAVE; ++r) {
        float s = 0.0f;
        #pragma unroll
        for (int k = 0; k < 4; ++k)
            s += a[r][k].f.x * w[r][k].f.x + a[r][k].f.y * w[r][k].f.y;
        dot[r] = s;
    }

    // --- batched butterfly: 6 steps x 4 independent chains ---
    #pragma unroll
    for (int off = 32; off > 0; off >>= 1) {
        #pragma unroll
        for (int r = 0; r < ROWS_PER_WAVE; ++r)
            dot[r] += __shfl_xor(dot[r], off, 64);
    }
    // every lane holds all 4 complete dots.

    const int sel = lane & 3;
    float v = dot[0];
    #pragma unroll
    for (int r = 1; r < ROWS_PER_WAVE; ++r)
        v = (sel == r) ? dot[r] : v;

    const float pa = 12.0f * tanhf(v);

    float contrib = 0.0f;
    if (lane < ROWS_PER_WAVE) {
        out[1 + b0 + lane] = pa;
        const float d  = pa - factor[b0 + lane];
        const float ad = fabsf(d);
        contrib = (ad < 1.0f) ? 0.5f * d * d : (ad - 0.5f);
    }
    contrib += __shfl_xor(contrib, 2, 64);
    contrib += __shfl_xor(contrib, 1, 64);

    __shared__ float sh[WAVES_PER_BLOCK];
    if (lane == 0) sh[wave] = contrib;
    __syncthreads();
    if (threadIdx.x == 0)
        partials[blockIdx.x] =
            ((sh[0] + sh[1]) + (sh[2] + sh[3])) * (1.0f / 65536.0f);
}

__global__ __launch_bounds__(256) void reduce_partials_kernel(
    const float* __restrict__ partials, float* __restrict__ out)
{
    __shared__ float sh[4];
    const int wave = threadIdx.x >> 6;
    const int lane = threadIdx.x & 63;

    float s = 0.0f;
    #pragma unroll
    for (int i = 0; i < NUM_BLOCKS / 256; ++i)
        s += partials[threadIdx.x + i * 256];

    #pragma unroll
    for (int off = 32; off > 0; off >>= 1)
        s += __shfl_xor(s, off, 64);

    if (lane == 0) sh[wave] = s;
    __syncthreads();
    if (threadIdx.x == 0)
        out[0] = (sh[0] + sh[1]) + (sh[2] + sh[3]);
}

extern "C" void kernel_launch(void* const* d_in, const int* in_sizes, int n_in,
                              void* d_out, int out_size, void* d_ws, size_t ws_size,
                              hipStream_t stream) {
    const float* input   = (const float*)d_in[0];
    const float* factor  = (const float*)d_in[1];
    const int*   label   = (const int*)d_in[2];
    const float* centers = (const float*)d_in[3];
    float* out      = (float*)d_out;
    float* partials = (float*)d_ws;   // NUM_BLOCKS floats, fully overwritten

    prediction_loss_kernel<<<NUM_BLOCKS, 256, 0, stream>>>(
        input, factor, label, centers, out, partials);
    reduce_partials_kernel<<<1, 256, 0, stream>>>(partials, out);
}